// Round 8
// baseline (378.202 us; speedup 1.0000x reference)
//
#include <hip/hip_runtime.h>
#include <math.h>

#define B_    16
#define N_    1024
#define G_    16      // blocks per batch
#define NW    8       // waves per block (8 rows/wave)
#define ITERS 100

typedef __attribute__((ext_vector_type(2))) float f32x2;

// ws layout: [cnt: B_*ITERS u32, pad to 8192][mu_den: 4*B_*N_ f32][nug: B_*N_ f32]
#define MUDEN_OFF   8192
#define MUDEN_BYTES (4 * B_ * N_ * 4)
#define NUG_OFF     (MUDEN_OFF + MUDEN_BYTES)
#define ZERO_BYTES  NUG_OFF     // cnt + all 4 mu_den buffers start at 0

__device__ __forceinline__ float fast_div(float num, float den) {
    float r = __builtin_amdgcn_rcpf(den);
    r = r * (2.0f - den * r);      // one Newton step -> ~full fp32 accuracy
    return num * r;
}

// Full 64-lane wave sum via DPP (zero DS-pipe ops, pure VALU). Proven R1-R7.
__device__ __forceinline__ float wave_sum64(float x) {
#define DPP_ADD(ctrl)                                                   \
    x += __int_as_float(__builtin_amdgcn_update_dpp(                    \
            0, __float_as_int(x), ctrl, 0xf, 0xf, false));
    DPP_ADD(0x111)  // row_shr:1
    DPP_ADD(0x112)  // row_shr:2
    DPP_ADD(0x114)  // row_shr:4
    DPP_ADD(0x118)  // row_shr:8
    DPP_ADD(0x142)  // row_bcast:15
    DPP_ADD(0x143)  // row_bcast:31
#undef DPP_ADD
    return __int_as_float(__builtin_amdgcn_readlane(__float_as_int(x), 63));
}

// R13 = R12 (8 rows/wave, proven 297us) with the VALU inflation removed:
//   - __launch_bounds__(512,1): R12's (512,2) made the allocator split the
//     256-reg budget into ~104 VGPR + AGPRs for u[8][16] -> ~256
//     v_accvgpr_read per wave per iter (VALU 730 instr/wave measured vs ~380
//     source-level). Relaxed cap keeps u in arch VGPRs (~190 total); HW
//     occupancy stays 2 waves/SIMD (block granularity), so nothing is lost.
//   - u stored as f32x2 pairs; PhiA/PhiB written as ext-vector mul+add ->
//     v_pk_fma_f32 (gfx950 packed fp32): 256 scalar FMA -> 128 packed.
// All proven structure unchanged: b128 LDS patterns (R9 lesson: lane-
// contiguous), wide gather (R10 lesson), counter barrier (R11 lesson),
// contiguous atomics (R7 lesson), 1 block/CU (R9 lesson).
// Ordering (validated R4/R5/R8): __syncthreads() drains vmcnt per wave before
// s_barrier, so atomics are at the L2 coherence point before tid 0's arrival
// add; readers use coherent atomic loads only after the poll sees 16 arrivals.
__global__ __launch_bounds__(512, 1)
void sinkhorn_kernel(const float* __restrict__ C, float* __restrict__ out,
                     float* __restrict__ mu_den, float* __restrict__ nug,
                     unsigned int* __restrict__ cnt)
{
    __shared__ float part[NW * 1024];   // 32 KB: per-wave column-partial slabs
    __shared__ float mu_s[N_];          // 4 KB: current mu

    const int tid = threadIdx.x;
    const int w   = tid >> 6;        // wave 0..7 -> 8-row group
    const int l   = tid & 63;
    // XCD-affinity swizzle: batch b's 16 blocks share bid%8 -> same XCD L2
    const int bid = blockIdx.x;
    const int xx = bid & 7, ss = bid >> 3;
    const int b = xx + ((ss >> 4) << 3);
    const int g = ss & 15;
    const int row0 = 64 * g + 8 * w;
    const float cons = 1.0f / 1024.0f;

    // ---- one-time: U tile = exp(-C/eps), columns 4*l + s + 256*ch ----
    // u2[rr][2*ch]   = {U(rr, 4ch+0), U(rr, 4ch+1)}
    // u2[rr][2*ch+1] = {U(rr, 4ch+2), U(rr, 4ch+3)}
    f32x2 u2[8][8];
    {
        const float* Cb = C + (size_t)b * N_ * N_ + (size_t)row0 * N_;
        #pragma unroll
        for (int rr = 0; rr < 8; ++rr)
            #pragma unroll
            for (int ch = 0; ch < 4; ++ch) {
                float4 cv = *(const float4*)(Cb + (size_t)rr * N_ + 4 * l + 256 * ch);
                u2[rr][2*ch]   = (f32x2){expf(-20.0f * cv.x), expf(-20.0f * cv.y)};
                u2[rr][2*ch+1] = (f32x2){expf(-20.0f * cv.z), expf(-20.0f * cv.w)};
            }
    }

    mu_s[tid]       = cons;
    mu_s[tid + 512] = cons;
    __syncthreads();

    for (int it = 0; it < ITERS; ++it) {
        // ---- Phase A: s_i = sum_j U_ij * mu_j (4x ds_read_b128 + pk-fma) ----
        f32x2 a2[8];
        #pragma unroll
        for (int rr = 0; rr < 8; ++rr) a2[rr] = (f32x2){0.f, 0.f};
        #pragma unroll
        for (int ch = 0; ch < 4; ++ch) {
            float4 mv = *(const float4*)&mu_s[4 * l + 256 * ch];
            const f32x2 m01 = (f32x2){mv.x, mv.y};
            const f32x2 m23 = (f32x2){mv.z, mv.w};
            #pragma unroll
            for (int rr = 0; rr < 8; ++rr) {
                a2[rr] += u2[rr][2*ch]   * m01;   // v_pk_fma_f32
                a2[rr] += u2[rr][2*ch+1] * m23;   // v_pk_fma_f32
            }
        }
        float a0 = wave_sum64(a2[0].x + a2[0].y);
        float a1 = wave_sum64(a2[1].x + a2[1].y);
        float a3_ = 0.f;  // (names kept scalar; no dynamic indexing)
        float a2s = wave_sum64(a2[2].x + a2[2].y);
        a3_ = wave_sum64(a2[3].x + a2[3].y);
        float a4 = wave_sum64(a2[4].x + a2[4].y);
        float a5 = wave_sum64(a2[5].x + a2[5].y);
        float a6 = wave_sum64(a2[6].x + a2[6].y);
        float a7 = wave_sum64(a2[7].x + a2[7].y);
        float nu0 = fast_div(cons, a0),  nu1 = fast_div(cons, a1);
        float nu2 = fast_div(cons, a2s), nu3 = fast_div(cons, a3_);
        float nu4 = fast_div(cons, a4),  nu5 = fast_div(cons, a5);
        float nu6 = fast_div(cons, a6),  nu7 = fast_div(cons, a7);

        if (it == ITERS - 1 && l < 8) {   // publish final nu chunk (coherent)
            float nv = (l == 0) ? nu0 : (l == 1) ? nu1 : (l == 2) ? nu2 :
                       (l == 3) ? nu3 : (l == 4) ? nu4 : (l == 5) ? nu5 :
                       (l == 6) ? nu6 : nu7;
            __hip_atomic_store(&nug[b * N_ + row0 + l], nv,
                               __ATOMIC_RELAXED, __HIP_MEMORY_SCOPE_AGENT);
        }

        const f32x2 nur2[8] = {
            (f32x2){nu0, nu0}, (f32x2){nu1, nu1}, (f32x2){nu2, nu2},
            (f32x2){nu3, nu3}, (f32x2){nu4, nu4}, (f32x2){nu5, nu5},
            (f32x2){nu6, nu6}, (f32x2){nu7, nu7}};

        // ---- Phase B: per-wave column partials -> slab (4x ds_write_b128,
        //      lane-contiguous 16B stride; pk-fma accumulation) ----
        // (no sync needed before this: iter it-1's gather reads finished
        //  before S2 of it-1 < here; part[] and mu_s[] are separate arrays)
        #pragma unroll
        for (int ch = 0; ch < 4; ++ch) {
            f32x2 pxy = (f32x2){0.f, 0.f};
            f32x2 pzw = (f32x2){0.f, 0.f};
            #pragma unroll
            for (int rr = 0; rr < 8; ++rr) {
                pxy += u2[rr][2*ch]   * nur2[rr];   // v_pk_fma_f32
                pzw += u2[rr][2*ch+1] * nur2[rr];   // v_pk_fma_f32
            }
            float4 p;
            p.x = pxy.x; p.y = pxy.y; p.z = pzw.x; p.w = pzw.y;
            *(float4*)&part[w * 1024 + 4 * l + 256 * ch] = p;
        }
        __syncthreads();   // S1: slabs complete

        // column sums across 8 slabs (wide: all 8 waves, conflict-free b32,
        // 2 columns per thread); TWO contiguous f32 atomics per thread
        const int buf = it & 3;
        {
            float s0 = 0.f, s1 = 0.f;
            #pragma unroll
            for (int w2 = 0; w2 < NW; ++w2) {
                s0 += part[w2 * 1024 + tid];
                s1 += part[w2 * 1024 + tid + 512];
            }
            float* md = &mu_den[((size_t)buf * B_ + b) * N_];
            unsafeAtomicAdd(md + tid,       s0);
            unsafeAtomicAdd(md + tid + 512, s1);
        }

        // ---- fence-free device barrier among the 16 blocks of batch b ----
        __syncthreads();   // S2: each wave's vmcnt(0) -> adds at coherence pt
        if (tid == 0) {
            unsigned int* c = &cnt[b * ITERS + it];
            __hip_atomic_fetch_add(c, 1u, __ATOMIC_RELAXED, __HIP_MEMORY_SCOPE_AGENT);
            while (__hip_atomic_load(c, __ATOMIC_RELAXED, __HIP_MEMORY_SCOPE_AGENT) < G_)
                __builtin_amdgcn_s_sleep(1);
        }
        __syncthreads();   // S3

        // ---- readback -> new mu; zero the buffer for iter it+2 ----
        {
            const float* mdb = &mu_den[((size_t)buf * B_ + b) * N_];
            float den0 = __hip_atomic_load(mdb + tid,
                                           __ATOMIC_RELAXED, __HIP_MEMORY_SCOPE_AGENT);
            float den1 = __hip_atomic_load(mdb + tid + 512,
                                           __ATOMIC_RELAXED, __HIP_MEMORY_SCOPE_AGENT);
            mu_s[tid]       = fast_div(cons, den0);
            mu_s[tid + 512] = fast_div(cons, den1);
        }
        if (tid < 64)   // my block's 1/16 share of the buffer reused at it+2
            __hip_atomic_store(&mu_den[((size_t)((it + 2) & 3) * B_ + b) * N_ + 64 * g + tid],
                               0.0f, __ATOMIC_RELAXED, __HIP_MEMORY_SCOPE_AGENT);
        __syncthreads();   // S4: mu_s ready for next phase A
    }

    // ---- epilogue: T_ij = mu_i * U_ij * nu_j (float4 stores) ----
    float mu_i[8];
    #pragma unroll
    for (int rr = 0; rr < 8; ++rr)
        mu_i[rr] = mu_s[row0 + rr];          // broadcast read

    float* ob = out + (size_t)b * N_ * N_ + (size_t)row0 * N_;
    #pragma unroll
    for (int ch = 0; ch < 4; ++ch) {
        const int cbase = b * N_ + 4 * l + 256 * ch;
        float4 nuv;
        nuv.x = __hip_atomic_load(&nug[cbase + 0], __ATOMIC_RELAXED, __HIP_MEMORY_SCOPE_AGENT);
        nuv.y = __hip_atomic_load(&nug[cbase + 1], __ATOMIC_RELAXED, __HIP_MEMORY_SCOPE_AGENT);
        nuv.z = __hip_atomic_load(&nug[cbase + 2], __ATOMIC_RELAXED, __HIP_MEMORY_SCOPE_AGENT);
        nuv.w = __hip_atomic_load(&nug[cbase + 3], __ATOMIC_RELAXED, __HIP_MEMORY_SCOPE_AGENT);
        const f32x2 nv01 = (f32x2){nuv.x, nuv.y};
        const f32x2 nv23 = (f32x2){nuv.z, nuv.w};
        #pragma unroll
        for (int rr = 0; rr < 8; ++rr) {
            const f32x2 mu2 = (f32x2){mu_i[rr], mu_i[rr]};
            f32x2 t01 = mu2 * u2[rr][2*ch]   * nv01;
            f32x2 t23 = mu2 * u2[rr][2*ch+1] * nv23;
            float4 t;
            t.x = t01.x; t.y = t01.y; t.z = t23.x; t.w = t23.y;
            *(float4*)(ob + (size_t)rr * N_ + 4 * l + 256 * ch) = t;
        }
    }
}

extern "C" void kernel_launch(void* const* d_in, const int* in_sizes, int n_in,
                              void* d_out, int out_size, void* d_ws, size_t ws_size,
                              hipStream_t stream) {
    const float* C = (const float*)d_in[2];     // (B, N, N); x,y unused
    float* out = (float*)d_out;

    unsigned char* ws = (unsigned char*)d_ws;
    unsigned int* cnt = (unsigned int*)ws;
    float* mu_den = (float*)(ws + MUDEN_OFF);
    float* nug    = (float*)(ws + NUG_OFF);

    // cnt + mu_den buffers must start at zero (buffers 2,3 are re-zeroed
    // in-kernel during iters 0,1 as part of the rotation anyway)
    hipMemsetAsync(ws, 0, ZERO_BYTES, stream);
    hipLaunchKernelGGL(sinkhorn_kernel, dim3(256), dim3(512), 0, stream,
                       C, out, mu_den, nug, cnt);
}